// Round 2
// 117.169 us; speedup vs baseline: 1.0127x; 1.0127x over previous
//
#include <hip/hip_runtime.h>

#define WST 72   // f16 LDS row stride (144 B = 9*16: aligned, benign banks)

typedef __attribute__((ext_vector_type(4))) float    f32x4;
typedef __attribute__((ext_vector_type(2))) float    f32x2;
typedef __attribute__((ext_vector_type(8))) _Float16 f16x8;
typedef __attribute__((ext_vector_type(2))) _Float16 f16x2;
typedef __attribute__((ext_vector_type(2))) __fp16   fp16x2_raw;

union U8 { f16x8 v; f16x2 h[4]; };

__device__ __forceinline__ float rcp_f(float x) { return __builtin_amdgcn_rcpf(x); }
__device__ __forceinline__ float fast_sigmoid(float x) {
    return rcp_f(1.0f + __expf(-x));
}
__device__ __forceinline__ float tanh_exp(float x) {
    return 1.0f - 2.0f * rcp_f(__expf(2.0f * x) + 1.0f);
}
__device__ __forceinline__ f16x2 pkrtz(float a, float b) {
    fp16x2_raw r = __builtin_amdgcn_cvt_pkrtz(a, b);
    return __builtin_bit_cast(f16x2, r);
}

// ---- weight staging: global f32 -> LDS f16 transposed (Wt[c*WST+k] = W[k][c]) ----
__device__ __forceinline__ void wload8(const float* __restrict__ W, int tid, float v[8]) {
#pragma unroll
    for (int i = 0; i < 8; ++i) v[i] = W[tid + i * 512];
}
__device__ __forceinline__ void wstore8(_Float16* Wt, int tid, const float v[8], float scale) {
#pragma unroll
    for (int i = 0; i < 8; ++i) {
        int idx = tid + i * 512;
        Wt[(idx & 63) * WST + (idx >> 6)] = (_Float16)(v[i] * scale);
    }
}
__device__ __forceinline__ void wload16(const float* __restrict__ W, int t256, float v[16]) {
#pragma unroll
    for (int i = 0; i < 16; ++i) v[i] = W[t256 + i * 256];
}
__device__ __forceinline__ void wstore16(_Float16* Wt, int t256, const float v[16]) {
#pragma unroll
    for (int i = 0; i < 16; ++i) {
        int idx = t256 + i * 256;
        Wt[(idx & 63) * WST + (idx >> 6)] = (_Float16)v[i];
    }
}

// one 16x16(x64) strip of a 64x64x64 GEMM: wave covers rows [arow..), cols
// [colb, colb+16) and [colb+16, colb+32). acc pre-loaded with bias.
__device__ __forceinline__ void gemm2(const _Float16* Act, int arow, int qd,
                                      const _Float16* Wt, int colb,
                                      f32x4 acc[2]) {
    f16x8 a0 = *(const f16x8*)(Act + arow * WST + qd * 8);
    f16x8 a1 = *(const f16x8*)(Act + arow * WST + 32 + qd * 8);
#pragma unroll
    for (int cc = 0; cc < 2; ++cc) {
        const _Float16* wr = Wt + (colb + cc * 16) * WST + qd * 8;
        f16x8 b0 = *(const f16x8*)(wr);
        f16x8 b1 = *(const f16x8*)(wr + 32);
        acc[cc] = __builtin_amdgcn_mfma_f32_16x16x32_f16(a0, b0, acc[cc], 0, 0, 0);
        acc[cc] = __builtin_amdgcn_mfma_f32_16x16x32_f16(a1, b1, acc[cc], 0, 0, 0);
    }
}

// ---------------------------------------------------------------------------
// fused_all: block = (n, j-half). 6-phase dual-chain prep (waves 0-3 = m-chain,
// waves 4-7 = g-chain), then binary all-pairs with paired-rcp tanh and the
// (1-2r) affine folded into -2*W + column-sum bias. Zero global intermediates.
// ---------------------------------------------------------------------------
__global__ __launch_bounds__(512, 2) void fused_all_kernel(
    const float* __restrict__ x,
    const float* __restrict__ W_lin, const float* __restrict__ b_lin,
    const float* __restrict__ Wu1,  const float* __restrict__ bu1,
    const float* __restrict__ Wu2,  const float* __restrict__ bu2,
    const float* __restrict__ Wug1, const float* __restrict__ bug1,
    const float* __restrict__ Wug2, const float* __restrict__ bug2,
    const float* __restrict__ Wb1,  const float* __restrict__ bb1,
    const float* __restrict__ Wb2,  const float* __restrict__ bb2,
    const float* __restrict__ Wbg1, const float* __restrict__ bbg1,
    const float* __restrict__ Wbg2, const float* __restrict__ bbg2,
    float* __restrict__ out)
{
    __shared__ __align__(16) char smem[113664];
    _Float16* Wt0  = (_Float16*)(smem);            // 9216  rotating weight slot
    _Float16* Wt1  = (_Float16*)(smem + 9216);     // 9216  rotating weight slot (-2*Wb2 in binary)
    _Float16* Ax   = (_Float16*)(smem + 18432);    // 9216  x-act -> Wbg1P -> {Tu, Tg}
    _Float16* Tu   = (_Float16*)(smem + 18432);    //   32x72 f16 = 4608
    _Float16* Tg   = (_Float16*)(smem + 23040);    //   32x72 f16 = 4608
    _Float16* Ah   = (_Float16*)(smem + 27648);    // 9216  h (all 64 rows); dead after P4
    float*    csum_m = (float*)(smem + 27648);     //   64 f32 (aliases dead Ah)
    float*    csum_g = (float*)(smem + 27904);     //   64 f32
    _Float16* Au   = (_Float16*)(smem + 36864);    // 9216  Wb1Q -> Wug1 -> -2*Wbg2
    _Float16* Agg  = (_Float16*)(smem + 46080);    // 9216  Wu2
    float*    EQb  = (float*)(smem + 55296);       // 16384 (64x64 f32)
    float*    EQgb = (float*)(smem + 71680);       // 16384
    float*    EPm  = (float*)(smem + 88064);       // 8704  (32x68 f32)
    float*    EPgm = (float*)(smem + 96768);       // 8704
    float*    um32 = (float*)(smem + 105472);      // 8192  (32x64 f32)
    float*    Red  = (float*)(smem);               // 32768 alias Wt0..Ah (post-loop only)

    int tid = threadIdx.x, w = tid >> 6, l = tid & 63;
    int qd = l >> 4, l16 = l & 15;
    int n = blockIdx.x >> 1, jsel = blockIdx.x & 1;

    // full 64x64 gemm mapping (P1): 4 row-quarters x 2 col-halves
    int rw = w & 3, ch = w >> 2;
    int arow = rw * 16 + l16;
    int colb = ch * 32 + l16;
    int crow = rw * 16 + qd * 4;

    // dual-chain mapping (P2-P4): waves 0-3 = chain m (gA), waves 4-7 = chain g
    bool gA = (w < 4);
    int w2 = w & 3;
    int t256 = tid & 255;
    int lr16 = (w2 & 1) * 16;                // local row base for 32-row gemms
    int cb32 = (w2 >> 1) * 32;               // col base for 32-row gemms
    int arow32 = jsel * 32 + lr16 + l16;     // A-row in Ah for own-half gemms

    // ---- P0: stage x -> Ax (f16), W_lin -> Wt0 ----
#pragma unroll
    for (int i = 0; i < 4; ++i) {
        int e = tid * 2 + i * 1024;
        f32x2 v = *(const f32x2*)(x + (size_t)n * 4096 + e);
        f16x2 p; p[0] = (_Float16)v[0]; p[1] = (_Float16)v[1];
        *(f16x2*)(Ax + (e >> 6) * WST + (e & 63)) = p;
    }
    {
        float wv[8];
        wload8(W_lin, tid, wv);
        wstore8(Wt0, tid, wv, 1.0f);
    }
    __syncthreads();

    // ---- P1: h = x@W_lin + b_lin -> Ah (all 8 waves);
    //          stage Wb1P -> Wt1 (gA), Wb1Q -> Au (gB) ----
    {
        float wv[16];
        wload16(gA ? Wb1 : Wb1 + 4096, t256, wv);
        f32x4 acc[2];
#pragma unroll
        for (int cc = 0; cc < 2; ++cc) {
            float bv = b_lin[colb + cc * 16];
            acc[cc] = (f32x4){bv, bv, bv, bv};
        }
        gemm2(Ax, arow, qd, Wt0, colb, acc);
#pragma unroll
        for (int cc = 0; cc < 2; ++cc)
#pragma unroll
            for (int r = 0; r < 4; ++r)
                Ah[(crow + r) * WST + colb + cc * 16] = (_Float16)acc[cc][r];
        wstore16(gA ? Wt1 : Au, t256, wv);
    }
    __syncthreads();

    // ---- P2: gA: EP = exp(2(h@Wb1P+bb1)) -> EPm (own 32 rows);
    //          gB: EQ = exp(2(h@Wb1Q))     -> EQb (all 64 rows);
    //          stage Wbg1P -> Ax (gA), Wbg1Q -> Wt0 (gB) ----
    {
        float wv[16];
        wload16(gA ? Wbg1 : Wbg1 + 4096, t256, wv);
        if (gA) {
            f32x4 acc[2];
#pragma unroll
            for (int cc = 0; cc < 2; ++cc) {
                float bv = bb1[cb32 + cc * 16 + l16];
                acc[cc] = (f32x4){bv, bv, bv, bv};
            }
            gemm2(Ah, arow32, qd, Wt1, cb32 + l16, acc);
#pragma unroll
            for (int cc = 0; cc < 2; ++cc)
#pragma unroll
                for (int r = 0; r < 4; ++r)
                    EPm[(lr16 + qd * 4 + r) * 68 + cb32 + cc * 16 + l16] =
                        __expf(2.0f * acc[cc][r]);
            wstore16(Ax, t256, wv);
        } else {
            f32x4 a4[2][2];
#pragma unroll
            for (int hh = 0; hh < 2; ++hh) {
                a4[hh][0] = (f32x4){0.f, 0.f, 0.f, 0.f};
                a4[hh][1] = (f32x4){0.f, 0.f, 0.f, 0.f};
            }
            gemm2(Ah, w2 * 16 + l16, qd, Au, l16, a4[0]);
            gemm2(Ah, w2 * 16 + l16, qd, Au, 32 + l16, a4[1]);
#pragma unroll
            for (int hh = 0; hh < 2; ++hh)
#pragma unroll
                for (int cc = 0; cc < 2; ++cc)
#pragma unroll
                    for (int r = 0; r < 4; ++r)
                        EQb[(w2 * 16 + qd * 4 + r) * 64 + hh * 32 + cc * 16 + l16] =
                            __expf(2.0f * a4[hh][cc][r]);
            wstore16(Wt0, t256, wv);
        }
    }
    __syncthreads();

    // ---- P3: gA: EPg -> EPgm (B=Ax);  gB: EQg -> EQgb (B=Wt0);
    //          stage Wu1 -> Wt1 (gA), Wug1 -> Au (gB) ----
    {
        float wv[16];
        wload16(gA ? Wu1 : Wug1, t256, wv);
        if (gA) {
            f32x4 acc[2];
#pragma unroll
            for (int cc = 0; cc < 2; ++cc) {
                float bv = bbg1[cb32 + cc * 16 + l16];
                acc[cc] = (f32x4){bv, bv, bv, bv};
            }
            gemm2(Ah, arow32, qd, Ax, cb32 + l16, acc);
#pragma unroll
            for (int cc = 0; cc < 2; ++cc)
#pragma unroll
                for (int r = 0; r < 4; ++r)
                    EPgm[(lr16 + qd * 4 + r) * 68 + cb32 + cc * 16 + l16] =
                        __expf(2.0f * acc[cc][r]);
            wstore16(Wt1, t256, wv);
        } else {
            f32x4 a4[2][2];
#pragma unroll
            for (int hh = 0; hh < 2; ++hh) {
                a4[hh][0] = (f32x4){0.f, 0.f, 0.f, 0.f};
                a4[hh][1] = (f32x4){0.f, 0.f, 0.f, 0.f};
            }
            gemm2(Ah, w2 * 16 + l16, qd, Wt0, l16, a4[0]);
            gemm2(Ah, w2 * 16 + l16, qd, Wt0, 32 + l16, a4[1]);
#pragma unroll
            for (int hh = 0; hh < 2; ++hh)
#pragma unroll
                for (int cc = 0; cc < 2; ++cc)
#pragma unroll
                    for (int r = 0; r < 4; ++r)
                        EQgb[(w2 * 16 + qd * 4 + r) * 64 + hh * 32 + cc * 16 + l16] =
                            __expf(2.0f * a4[hh][cc][r]);
            wstore16(Au, t256, wv);
        }
    }
    __syncthreads();

    // ---- P4: gA: T1u = tanh(h@Wu1+bu1) -> Tu (own 32 rows);
    //          gB: T1g = tanh(h@Wug1+bug1) -> Tg (own 32 rows);
    //          stage Wu2 -> Agg (gA), Wug2 -> Wt0 (gB) ----
    {
        float wv[16];
        wload16(gA ? Wu2 : Wug2, t256, wv);
        const _Float16* Bw = gA ? Wt1 : Au;
        const float* bias1 = gA ? bu1 : bug1;
        _Float16* Tdst = gA ? Tu : Tg;
        f32x4 acc[2];
#pragma unroll
        for (int cc = 0; cc < 2; ++cc) {
            float bv = bias1[cb32 + cc * 16 + l16];
            acc[cc] = (f32x4){bv, bv, bv, bv};
        }
        gemm2(Ah, arow32, qd, Bw, cb32 + l16, acc);
#pragma unroll
        for (int cc = 0; cc < 2; ++cc)
#pragma unroll
            for (int r = 0; r < 4; ++r)
                Tdst[(lr16 + qd * 4 + r) * WST + cb32 + cc * 16 + l16] =
                    (_Float16)tanh_exp(acc[cc][r]);
        wstore16(gA ? Agg : Wt0, t256, wv);
    }
    __syncthreads();

    // ---- P5: U = T1u@Wu2+bu2, G = T1g@Wug2+bug2, um = U*sig(G) -> um32;
    //          stage -2*Wb2 -> Wt1, -2*Wbg2 -> Au;
    //          csum = bias + colsum(f16-rounded W) for the (1-2r) fold ----
    {
        float wm[8], wg2[8];
        wload8(Wb2, tid, wm);
        wload8(Wbg2, tid, wg2);
        float cs = 0.0f;
        bool docs = (w < 2);                 // waves 0,1 (wave-uniform)
        if (docs) {
            const float* Wp = (w == 0) ? Wb2 : Wbg2;
            int c = tid & 63;
#pragma unroll
            for (int k = 0; k < 64; ++k)
                cs += (float)(_Float16)Wp[k * 64 + c];   // f16-rounded: exact fold
            cs += ((w == 0) ? bb2 : bbg2)[c];
        }
        int rw5 = w & 1, ch5 = w >> 1;
        int ar5 = (rw5 * 16 + l16) * WST;
        int c5 = ch5 * 16 + l16;
        f16x8 a0 = *(const f16x8*)(Tu + ar5 + qd * 8);
        f16x8 a1 = *(const f16x8*)(Tu + ar5 + 32 + qd * 8);
        f16x8 b0 = *(const f16x8*)(Agg + c5 * WST + qd * 8);
        f16x8 b1 = *(const f16x8*)(Agg + c5 * WST + 32 + qd * 8);
        float bv = bu2[c5];
        f32x4 ua = (f32x4){bv, bv, bv, bv};
        ua = __builtin_amdgcn_mfma_f32_16x16x32_f16(a0, b0, ua, 0, 0, 0);
        ua = __builtin_amdgcn_mfma_f32_16x16x32_f16(a1, b1, ua, 0, 0, 0);
        a0 = *(const f16x8*)(Tg + ar5 + qd * 8);
        a1 = *(const f16x8*)(Tg + ar5 + 32 + qd * 8);
        b0 = *(const f16x8*)(Wt0 + c5 * WST + qd * 8);
        b1 = *(const f16x8*)(Wt0 + c5 * WST + 32 + qd * 8);
        bv = bug2[c5];
        f32x4 ga = (f32x4){bv, bv, bv, bv};
        ga = __builtin_amdgcn_mfma_f32_16x16x32_f16(a0, b0, ga, 0, 0, 0);
        ga = __builtin_amdgcn_mfma_f32_16x16x32_f16(a1, b1, ga, 0, 0, 0);
#pragma unroll
        for (int r = 0; r < 4; ++r)
            um32[(rw5 * 16 + qd * 4 + r) * 64 + c5] = ua[r] * fast_sigmoid(ga[r]);
        wstore8(Wt1, tid, wm, -2.0f);
        wstore8(Au, tid, wg2, -2.0f);
        if (docs) ((w == 0) ? csum_m : csum_g)[tid & 63] = cs;
    }
    __syncthreads();

    // =============== binary phase ===============
    int jgrp = w >> 2, iw = w & 3;      // 2 j-groups x 4 i-ranges

    // B fragments (-2*W, all 64 cols) from transposed weights in LDS
    f16x8 bwm[4][2], bwg[4][2];
#pragma unroll
    for (int cc = 0; cc < 4; ++cc)
#pragma unroll
        for (int kk = 0; kk < 2; ++kk) {
            bwm[cc][kk] = *(const f16x8*)(Wt1 + (cc * 16 + l16) * WST + kk * 32 + qd * 8);
            bwg[cc][kk] = *(const f16x8*)(Au  + (cc * 16 + l16) * WST + kk * 32 + qd * 8);
        }
    float bim[4], big[4];
#pragma unroll
    for (int cc = 0; cc < 4; ++cc) {
        bim[cc] = csum_m[cc * 16 + l16];   // bb2 + colsum(Wb2): (1-2r) fold
        big[cc] = csum_g[cc * 16 + l16];
    }

    // P fragments (loop-invariant, register-resident)
    const float* pr  = EPm  + (jgrp * 16 + l16) * 68;
    const float* pgr = EPgm + (jgrp * 16 + l16) * 68;
    f32x4 pm[4], pg[4];
    pm[0] = *(const f32x4*)(pr + qd * 8);
    pm[1] = *(const f32x4*)(pr + qd * 8 + 4);
    pm[2] = *(const f32x4*)(pr + 32 + qd * 8);
    pm[3] = *(const f32x4*)(pr + 32 + qd * 8 + 4);
    pg[0] = *(const f32x4*)(pgr + qd * 8);
    pg[1] = *(const f32x4*)(pgr + qd * 8 + 4);
    pg[2] = *(const f32x4*)(pgr + 32 + qd * 8);
    pg[3] = *(const f32x4*)(pgr + 32 + qd * 8 + 4);

    f32x4 bacc[4];
#pragma unroll
    for (int cc = 0; cc < 4; ++cc) bacc[cc] = (f32x4){0.f, 0.f, 0.f, 0.f};

    for (int ii = iw * 16; ii < iw * 16 + 16; ++ii) {
        const float* qm = EQb  + ii * 64;
        const float* qg = EQgb + ii * 64;
        U8 am[2], ag[2];
#pragma unroll
        for (int kk = 0; kk < 2; ++kk) {
            int cb = kk * 32 + qd * 8;
            f32x4 qa = *(const f32x4*)(qm + cb);
            f32x4 qb = *(const f32x4*)(qm + cb + 4);
            f32x4 ha = *(const f32x4*)(qg + cb);
            f32x4 hb = *(const f32x4*)(qg + cb + 4);
#pragma unroll
            for (int t = 0; t < 2; ++t) {
                // paired reciprocal: 1/a0,1/a1 from one rcp(a0*a1)
                float a0 = __builtin_fmaf(pm[kk*2][2*t],   qa[2*t],   1.0f);
                float a1 = __builtin_fmaf(pm[kk*2][2*t+1], qa[2*t+1], 1.0f);
                float ri = rcp_f(a0 * a1);
                am[kk].h[t]     = pkrtz(ri * a1, ri * a0);
                float b0f = __builtin_fmaf(pm[kk*2+1][2*t],   qb[2*t],   1.0f);
                float b1f = __builtin_fmaf(pm[kk*2+1][2*t+1], qb[2*t+1], 1.0f);
                float rj = rcp_f(b0f * b1f);
                am[kk].h[2 + t] = pkrtz(rj * b1f, rj * b0f);
                float c0 = __builtin_fmaf(pg[kk*2][2*t],   ha[2*t],   1.0f);
                float c1 = __builtin_fmaf(pg[kk*2][2*t+1], ha[2*t+1], 1.0f);
                float rk = rcp_f(c0 * c1);
                ag[kk].h[t]     = pkrtz(rk * c1, rk * c0);
                float d0 = __builtin_fmaf(pg[kk*2+1][2*t],   hb[2*t],   1.0f);
                float d1 = __builtin_fmaf(pg[kk*2+1][2*t+1], hb[2*t+1], 1.0f);
                float rl = rcp_f(d0 * d1);
                ag[kk].h[2 + t] = pkrtz(rl * d1, rl * d0);
            }
        }
#pragma unroll
        for (int cc = 0; cc < 4; ++cc) {
            f32x4 d = {bim[cc], bim[cc], bim[cc], bim[cc]};
            d = __builtin_amdgcn_mfma_f32_16x16x32_f16(am[0].v, bwm[cc][0], d, 0, 0, 0);
            d = __builtin_amdgcn_mfma_f32_16x16x32_f16(am[1].v, bwm[cc][1], d, 0, 0, 0);
            f32x4 e = {big[cc], big[cc], big[cc], big[cc]};
            e = __builtin_amdgcn_mfma_f32_16x16x32_f16(ag[0].v, bwg[cc][0], e, 0, 0, 0);
            e = __builtin_amdgcn_mfma_f32_16x16x32_f16(ag[1].v, bwg[cc][1], e, 0, 0, 0);
#pragma unroll
            for (int r = 0; r < 4; ++r)
                bacc[cc][r] += d[r] * fast_sigmoid(e[r]);
        }
    }

    __syncthreads();   // all waves past frag setup + loop before Red overwrites
#pragma unroll
    for (int cc = 0; cc < 4; ++cc)
#pragma unroll
        for (int r = 0; r < 4; ++r)
            Red[(jgrp * 4 + iw) * 1024 + (qd * 4 + r) * 64 + cc * 16 + l16] = bacc[cc][r];
    __syncthreads();

    // reduce 4 i-ranges, add unary, write out
    {
        int e = tid * 4;                 // 512 thr x 4 = 2048 = 32x64
        int lr = e >> 6, col = e & 63;
        int g = lr >> 4, rr = lr & 15;
        f32x4 s = {0.f, 0.f, 0.f, 0.f};
#pragma unroll
        for (int w2r = 0; w2r < 4; ++w2r)
            s += *(const f32x4*)(Red + (g * 4 + w2r) * 1024 + rr * 64 + col);
        f32x4 u = *(const f32x4*)(um32 + lr * 64 + col);
        f32x4 o;
#pragma unroll
        for (int t = 0; t < 4; ++t)
            o[t] = u[t] + s[t] * (1.0f / 63.0f);
        *(f32x4*)(out + (size_t)n * 4096 + (size_t)(jsel * 32 + lr) * 64 + col) = o;
    }
}

extern "C" void kernel_launch(void* const* d_in, const int* in_sizes, int n_in,
                              void* d_out, int out_size, void* d_ws, size_t ws_size,
                              hipStream_t stream)
{
    (void)in_sizes; (void)n_in; (void)out_size; (void)d_ws; (void)ws_size;
    const float* x     = (const float*)d_in[0];
    const float* W_lin = (const float*)d_in[1];
    const float* b_lin = (const float*)d_in[2];
    const float* Wu1   = (const float*)d_in[3];
    const float* bu1   = (const float*)d_in[4];
    const float* Wu2   = (const float*)d_in[5];
    const float* bu2   = (const float*)d_in[6];
    const float* Wug1  = (const float*)d_in[7];
    const float* bug1  = (const float*)d_in[8];
    const float* Wug2  = (const float*)d_in[9];
    const float* bug2  = (const float*)d_in[10];
    const float* Wb1   = (const float*)d_in[11];
    const float* bb1   = (const float*)d_in[12];
    const float* Wb2   = (const float*)d_in[13];
    const float* bb2   = (const float*)d_in[14];
    const float* Wbg1  = (const float*)d_in[15];
    const float* bbg1  = (const float*)d_in[16];
    const float* Wbg2  = (const float*)d_in[17];
    const float* bbg2  = (const float*)d_in[18];

    hipLaunchKernelGGL(fused_all_kernel, dim3(256), dim3(512), 0, stream,
        x, W_lin, b_lin, Wu1, bu1, Wu2, bu2, Wug1, bug1, Wug2, bug2,
        Wb1, bb1, Wb2, bb2, Wbg1, bbg1, Wbg2, bbg2,
        (float*)d_out);
}